// Round 5
// baseline (352.483 us; speedup 1.0000x reference)
//
#include <hip/hip_runtime.h>
#include <hip/hip_fp16.h>

constexpr int D = 128;

// ---------------- small utility ----------------

__global__ void k_zero(int4* __restrict__ p, int n4) {
    int i = blockIdx.x * 256 + threadIdx.x;
    if (i < n4) p[i] = make_int4(0, 0, 0, 0);
}

// ---------------- CSR build ----------------

__global__ void k_count(const int* __restrict__ dst, int* __restrict__ cnt, int E) {
    int e = blockIdx.x * 256 + threadIdx.x;
    if (e < E) atomicAdd(&cnt[dst[e]], 1);
}

// dinv + per-block sum in one pass over cnt
__global__ __launch_bounds__(256) void k_deg_stats(const int* __restrict__ cnt,
                                                   float* __restrict__ dinv,
                                                   int* __restrict__ bsum, int n) {
    __shared__ int sm[256];
    int tid = threadIdx.x;
    int i = blockIdx.x * 256 + tid;
    int c = (i < n) ? cnt[i] : 0;
    if (i < n) dinv[i] = rsqrtf((float)(c + 1));  // +1 self-loop
    sm[tid] = c;
    __syncthreads();
    for (int off = 128; off > 0; off >>= 1) {
        if (tid < off) sm[tid] += sm[tid + off];
        __syncthreads();
    }
    if (tid == 0) bsum[blockIdx.x] = sm[0];
}

__global__ __launch_bounds__(1024) void k_scan_bsums(int* __restrict__ bsum, int nb,
                                                     int* __restrict__ rowptr, int n) {
    __shared__ int sm[1024];
    int tid = threadIdx.x;
    int v = (tid < nb) ? bsum[tid] : 0;
    sm[tid] = v;
    __syncthreads();
    for (int off = 1; off < 1024; off <<= 1) {
        int t = (tid >= off) ? sm[tid - off] : 0;
        __syncthreads();
        sm[tid] += t;
        __syncthreads();
    }
    if (tid < nb) bsum[tid] = sm[tid] - v;  // exclusive
    if (tid == 1023) rowptr[n] = sm[1023];
}

__global__ __launch_bounds__(256) void k_local_scan(const int* __restrict__ cnt,
                                                    const int* __restrict__ bsum,
                                                    int* __restrict__ rowptr,
                                                    int* __restrict__ cursor, int n) {
    __shared__ int sm[256];
    int tid = threadIdx.x;
    int i = blockIdx.x * 256 + tid;
    int v = (i < n) ? cnt[i] : 0;
    sm[tid] = v;
    __syncthreads();
    for (int off = 1; off < 256; off <<= 1) {
        int t = (tid >= off) ? sm[tid - off] : 0;
        __syncthreads();
        sm[tid] += t;
        __syncthreads();
    }
    if (i < n) {
        int rp = bsum[blockIdx.x] + sm[tid] - v;
        rowptr[i] = rp;
        cursor[i] = rp;
    }
}

template <typename IdxT>
__global__ void k_fill(const int* __restrict__ src, const int* __restrict__ dst,
                       int* __restrict__ cursor, IdxT* __restrict__ csr, int E) {
    int e = blockIdx.x * 256 + threadIdx.x;
    if (e < E) {
        int s = src[e], d = dst[e];
        int p = atomicAdd(&cursor[d], 1);
        csr[p] = (IdxT)s;
    }
}

// ---------------- fp32 -> fp16 with dinv pre-scale ----------------

__global__ void k_cvt_h(const float* __restrict__ in, const float* __restrict__ dinv,
                        __half* __restrict__ outh, int n4) {
    int i = blockIdx.x * 256 + threadIdx.x;
    if (i < n4) {
        float4 v = reinterpret_cast<const float4*>(in)[i];
        float dd = dinv[i >> 5];  // 32 float4 per row of 128
        __half ho[4] = {__float2half(v.x * dd), __float2half(v.y * dd),
                        __float2half(v.z * dd), __float2half(v.w * dd)};
        reinterpret_cast<uint2*>(outh)[i] = *reinterpret_cast<uint2*>(ho);
    }
}

// ---------------- W' = W2 @ M1 ; c' = b2 @ M1 + c1 ----------------

__global__ void k_wprime(const float* __restrict__ W2, const float* __restrict__ M1,
                         const float* __restrict__ b2, const float* __restrict__ c1,
                         float* __restrict__ Wp, float* __restrict__ cp) {
    int b = blockIdx.x, t = threadIdx.x;
    if (b < 64) {
        int idx = b * 256 + t;
        int i = idx >> 7, j = idx & 127;
        float acc = 0.f;
        for (int k = 0; k < 128; ++k) acc = fmaf(W2[i * 128 + k], M1[k * 128 + j], acc);
        Wp[idx] = acc;
    } else if (t < 128) {
        float acc = c1[t];
        for (int k = 0; k < 128; ++k) acc = fmaf(b2[k], M1[k * 128 + t], acc);
        cp[t] = acc;
    }
}

// ---------------- fused agg + GEMM ----------------
// Phase 1: per block, aggregate 64 rows t_i = dinv_i*(sum g_j + g_i) into LDS Ht[feat][row]
// Phase 2: GEMM from LDS: out = epilogue(t @ W + bias)
// MODE 0: out[N,128] = fp16( dinv[r] * relu(t@W + bias) )   (pre-scaled for next agg)
// MODE 1: out[N,1]   = relu(t@W + bias) . m2 + m2b[0]       (fp32)

template <int MODE, typename IdxT>
__global__ __launch_bounds__(512) void k_fused(const uint* __restrict__ Ah,  // packed half2 [n*64]
                                               const int* __restrict__ rowptr,
                                               const IdxT* __restrict__ csr,
                                               const float* __restrict__ dinv,
                                               const float* __restrict__ W,
                                               const float* __restrict__ bias,
                                               const float* __restrict__ m2,
                                               const float* __restrict__ m2b,
                                               void* __restrict__ outv, int n) {
    __shared__ float Ht[128 * 65];  // [feat][row], pad 65 (2-way write conflict = free)
    __shared__ float Wt[16 * 128];  // [k][col] slice
    int tid = threadIdx.x;
    int wv = tid >> 6;    // 0..7
    int lane = tid & 63;  // features 2*lane, 2*lane+1
    int r0 = blockIdx.x * 64;

    // ---- phase 1: aggregate rows r0 + wv*8 .. +7 ----
    for (int rr = 0; rr < 8; ++rr) {
        int lr = wv * 8 + rr;
        int i = r0 + lr;
        float accx = 0.f, accy = 0.f;
        if (i < n) {
            float di = dinv[i];
            uint g = Ah[i * 64 + lane];
            float2 a = __half22float2(*reinterpret_cast<const __half2*>(&g));
            accx = a.x;
            accy = a.y;
            int e = rowptr[i], end = rowptr[i + 1];
            for (; e + 4 <= end; e += 4) {
                int s0 = (int)csr[e];
                int s1 = (int)csr[e + 1];
                int s2 = (int)csr[e + 2];
                int s3 = (int)csr[e + 3];
                uint g0 = Ah[s0 * 64 + lane];
                uint g1 = Ah[s1 * 64 + lane];
                uint g2 = Ah[s2 * 64 + lane];
                uint g3 = Ah[s3 * 64 + lane];
                float2 v0 = __half22float2(*reinterpret_cast<const __half2*>(&g0));
                float2 v1 = __half22float2(*reinterpret_cast<const __half2*>(&g1));
                float2 v2 = __half22float2(*reinterpret_cast<const __half2*>(&g2));
                float2 v3 = __half22float2(*reinterpret_cast<const __half2*>(&g3));
                accx += v0.x + v1.x;
                accy += v0.y + v1.y;
                accx += v2.x + v3.x;
                accy += v2.y + v3.y;
            }
            for (; e < end; ++e) {
                int s0 = (int)csr[e];
                uint g0 = Ah[s0 * 64 + lane];
                float2 v0 = __half22float2(*reinterpret_cast<const __half2*>(&g0));
                accx += v0.x;
                accy += v0.y;
            }
            accx *= di;
            accy *= di;
        }
        Ht[(2 * lane) * 65 + lr] = accx;
        Ht[(2 * lane + 1) * 65 + lr] = accy;
    }
    __syncthreads();

    // ---- phase 2: GEMM from LDS ----
    int rg = tid >> 4;  // 0..31 -> rows rg*2, rg*2+1
    int cg = tid & 15;  // cols cg*8 .. +7
    float acc[2][8];
#pragma unroll
    for (int ri = 0; ri < 2; ++ri)
#pragma unroll
        for (int ci = 0; ci < 8; ++ci) acc[ri][ci] = 0.f;

    for (int k0 = 0; k0 < 128; k0 += 16) {
        {
            int kk = tid >> 5;
            int cc = (tid & 31) * 4;
            *reinterpret_cast<float4*>(&Wt[kk * 128 + cc]) =
                *reinterpret_cast<const float4*>(&W[(k0 + kk) * 128 + cc]);
        }
        __syncthreads();
#pragma unroll
        for (int k = 0; k < 16; ++k) {
            int kg = k0 + k;
            float a0 = Ht[kg * 65 + rg * 2];
            float a1 = Ht[kg * 65 + rg * 2 + 1];
            float4 b0 = *reinterpret_cast<float4*>(&Wt[k * 128 + cg * 8]);
            float4 b1 = *reinterpret_cast<float4*>(&Wt[k * 128 + cg * 8 + 4]);
            float bv[8] = {b0.x, b0.y, b0.z, b0.w, b1.x, b1.y, b1.z, b1.w};
#pragma unroll
            for (int ci = 0; ci < 8; ++ci) {
                acc[0][ci] = fmaf(a0, bv[ci], acc[0][ci]);
                acc[1][ci] = fmaf(a1, bv[ci], acc[1][ci]);
            }
        }
        __syncthreads();
    }

    float4 bb0 = *reinterpret_cast<const float4*>(&bias[cg * 8]);
    float4 bb1 = *reinterpret_cast<const float4*>(&bias[cg * 8 + 4]);
    float bv[8] = {bb0.x, bb0.y, bb0.z, bb0.w, bb1.x, bb1.y, bb1.z, bb1.w};

    if (MODE == 0) {
        __half* outh = (__half*)outv;
#pragma unroll
        for (int ri = 0; ri < 2; ++ri) {
            int r = r0 + rg * 2 + ri;
            if (r < n) {
                float dr = dinv[r];
                __half ho[8];
#pragma unroll
                for (int ci = 0; ci < 8; ++ci)
                    ho[ci] = __float2half(dr * fmaxf(acc[ri][ci] + bv[ci], 0.f));
                *reinterpret_cast<uint4*>(&outh[r * 128 + cg * 8]) =
                    *reinterpret_cast<const uint4*>(ho);
            }
        }
    } else {
        float* out = (float*)outv;
        float4 mm0 = *reinterpret_cast<const float4*>(&m2[cg * 8]);
        float4 mm1 = *reinterpret_cast<const float4*>(&m2[cg * 8 + 4]);
        float mv[8] = {mm0.x, mm0.y, mm0.z, mm0.w, mm1.x, mm1.y, mm1.z, mm1.w};
        float m2bv = m2b[0];
#pragma unroll
        for (int ri = 0; ri < 2; ++ri) {
            float p = 0.f;
#pragma unroll
            for (int ci = 0; ci < 8; ++ci) {
                float v = fmaxf(acc[ri][ci] + bv[ci], 0.f);
                p = fmaf(v, mv[ci], p);
            }
            p += __shfl_xor(p, 1);
            p += __shfl_xor(p, 2);
            p += __shfl_xor(p, 4);
            p += __shfl_xor(p, 8);
            int r = r0 + rg * 2 + ri;
            if (cg == 0 && r < n) out[r] = p + m2bv;
        }
    }
}

// ---------------- launch ----------------

extern "C" void kernel_launch(void* const* d_in, const int* in_sizes, int n_in,
                              void* d_out, int out_size, void* d_ws, size_t ws_size,
                              hipStream_t stream) {
    const float* x = (const float*)d_in[0];
    const int* ei = (const int*)d_in[1];
    const float* W0 = (const float*)d_in[2];
    const float* b0 = (const float*)d_in[3];
    const float* W1 = (const float*)d_in[4];
    const float* b1 = (const float*)d_in[5];
    const float* W2 = (const float*)d_in[6];
    const float* b2 = (const float*)d_in[7];
    const float* M1 = (const float*)d_in[8];
    const float* c1 = (const float*)d_in[9];
    const float* m2 = (const float*)d_in[10];
    const float* m2b = (const float*)d_in[11];
    float* out = (float*)d_out;

    int N = in_sizes[0] / D;
    int E = in_sizes[1] / 2;
    const int* src = ei;
    const int* dst = ei + E;

    char* ws = (char*)d_ws;
    size_t off = 0;
    auto alloc = [&](size_t bytes) -> void* {
        void* p = ws + off;
        off += (bytes + 255) & ~(size_t)255;
        return p;
    };

    int gN = (N + 255) / 256;
    int gE = (E + 255) / 256;
    int gFused = (N + 63) / 64;
    int nElem4 = N * D / 4;
    int gCvt = (nElem4 + 255) / 256;

    __half* bufH1 = (__half*)alloc((size_t)N * D * 2);
    __half* bufH2 = (__half*)alloc((size_t)N * D * 2);
    __half* xh = (__half*)alloc((size_t)N * D * 2);
    int* cnt = (int*)alloc((size_t)N * 4);
    float* dinv = (float*)alloc((size_t)N * 4);
    int* rowptr = (int*)alloc((size_t)(N + 1) * 4);
    int* cursor = (int*)alloc((size_t)N * 4);
    void* csr = alloc((size_t)E * 4);  // ushort (E*2) or uint (E*4)
    float* Wp = (float*)alloc((size_t)D * D * 4);
    float* cp = (float*)alloc((size_t)D * 4);
    int* bsum = (int*)alloc((size_t)gN * 4);

    bool small_idx = (N <= 65535);

    int zc = (N + 3) / 4;
    k_zero<<<(zc + 255) / 256, 256, 0, stream>>>((int4*)cnt, zc);
    k_count<<<gE, 256, 0, stream>>>(dst, cnt, E);
    k_deg_stats<<<gN, 256, 0, stream>>>(cnt, dinv, bsum, N);
    k_scan_bsums<<<1, 1024, 0, stream>>>(bsum, gN, rowptr, N);
    k_local_scan<<<gN, 256, 0, stream>>>(cnt, bsum, rowptr, cursor, N);
    if (small_idx)
        k_fill<ushort><<<gE, 256, 0, stream>>>(src, dst, cursor, (ushort*)csr, E);
    else
        k_fill<uint><<<gE, 256, 0, stream>>>(src, dst, cursor, (uint*)csr, E);
    k_cvt_h<<<gCvt, 256, 0, stream>>>(x, dinv, xh, nElem4);
    k_wprime<<<65, 256, 0, stream>>>(W2, M1, b2, c1, Wp, cp);

    auto fused0 = [&](const __half* in_h, const float* W, const float* b, __half* out_h) {
        if (small_idx)
            k_fused<0, ushort><<<gFused, 512, 0, stream>>>(
                (const uint*)in_h, rowptr, (const ushort*)csr, dinv, W, b, nullptr,
                nullptr, out_h, N);
        else
            k_fused<0, uint><<<gFused, 512, 0, stream>>>(
                (const uint*)in_h, rowptr, (const uint*)csr, dinv, W, b, nullptr,
                nullptr, out_h, N);
    };

    // layer 0
    fused0(xh, W0, b0, bufH1);
    // layer 1
    fused0(bufH1, W1, b1, bufH2);
    // layer 2 + fused MLP head
    if (small_idx)
        k_fused<1, ushort><<<gFused, 512, 0, stream>>>(
            (const uint*)bufH2, rowptr, (const ushort*)csr, dinv, Wp, cp, m2, m2b, out, N);
    else
        k_fused<1, uint><<<gFused, 512, 0, stream>>>(
            (const uint*)bufH2, rowptr, (const uint*)csr, dinv, Wp, cp, m2, m2b, out, N);
}

// Round 6
// 271.423 us; speedup vs baseline: 1.2987x; 1.2987x over previous
//
#include <hip/hip_runtime.h>
#include <hip/hip_fp16.h>

constexpr int D = 128;

// ---------------- small utility ----------------

__global__ void k_zero(int4* __restrict__ p, int n4) {
    int i = blockIdx.x * 256 + threadIdx.x;
    if (i < n4) p[i] = make_int4(0, 0, 0, 0);
}

// ---------------- CSR build ----------------

__global__ void k_count(const int* __restrict__ dst, int* __restrict__ cnt, int E) {
    int e = blockIdx.x * 256 + threadIdx.x;
    if (e < E) atomicAdd(&cnt[dst[e]], 1);
}

// dinv + per-block sum in one pass over cnt
__global__ __launch_bounds__(256) void k_deg_stats(const int* __restrict__ cnt,
                                                   float* __restrict__ dinv,
                                                   int* __restrict__ bsum, int n) {
    __shared__ int sm[256];
    int tid = threadIdx.x;
    int i = blockIdx.x * 256 + tid;
    int c = (i < n) ? cnt[i] : 0;
    if (i < n) dinv[i] = rsqrtf((float)(c + 1));  // +1 self-loop
    sm[tid] = c;
    __syncthreads();
    for (int off = 128; off > 0; off >>= 1) {
        if (tid < off) sm[tid] += sm[tid + off];
        __syncthreads();
    }
    if (tid == 0) bsum[blockIdx.x] = sm[0];
}

__global__ __launch_bounds__(1024) void k_scan_bsums(int* __restrict__ bsum, int nb,
                                                     int* __restrict__ rowptr, int n) {
    __shared__ int sm[1024];
    int tid = threadIdx.x;
    int v = (tid < nb) ? bsum[tid] : 0;
    sm[tid] = v;
    __syncthreads();
    for (int off = 1; off < 1024; off <<= 1) {
        int t = (tid >= off) ? sm[tid - off] : 0;
        __syncthreads();
        sm[tid] += t;
        __syncthreads();
    }
    if (tid < nb) bsum[tid] = sm[tid] - v;  // exclusive
    if (tid == 1023) rowptr[n] = sm[1023];
}

__global__ __launch_bounds__(256) void k_local_scan(const int* __restrict__ cnt,
                                                    const int* __restrict__ bsum,
                                                    int* __restrict__ rowptr,
                                                    int* __restrict__ cursor, int n) {
    __shared__ int sm[256];
    int tid = threadIdx.x;
    int i = blockIdx.x * 256 + tid;
    int v = (i < n) ? cnt[i] : 0;
    sm[tid] = v;
    __syncthreads();
    for (int off = 1; off < 256; off <<= 1) {
        int t = (tid >= off) ? sm[tid - off] : 0;
        __syncthreads();
        sm[tid] += t;
        __syncthreads();
    }
    if (i < n) {
        int rp = bsum[blockIdx.x] + sm[tid] - v;
        rowptr[i] = rp;
        cursor[i] = rp;
    }
}

template <typename IdxT>
__global__ void k_fill(const int* __restrict__ src, const int* __restrict__ dst,
                       int* __restrict__ cursor, IdxT* __restrict__ csr, int E) {
    int e = blockIdx.x * 256 + threadIdx.x;
    if (e < E) {
        int s = src[e], d = dst[e];
        int p = atomicAdd(&cursor[d], 1);
        csr[p] = (IdxT)s;
    }
}

// ---------------- fp32 -> fp16 with dinv pre-scale ----------------

__global__ void k_cvt_h(const float* __restrict__ in, const float* __restrict__ dinv,
                        __half* __restrict__ outh, int n4) {
    int i = blockIdx.x * 256 + threadIdx.x;
    if (i < n4) {
        float4 v = reinterpret_cast<const float4*>(in)[i];
        float dd = dinv[i >> 5];  // 32 float4 per row of 128
        __half ho[4] = {__float2half(v.x * dd), __float2half(v.y * dd),
                        __float2half(v.z * dd), __float2half(v.w * dd)};
        reinterpret_cast<uint2*>(outh)[i] = *reinterpret_cast<uint2*>(ho);
    }
}

// ---------------- W' = W2 @ M1 ; c' = b2 @ M1 + c1 ----------------

__global__ void k_wprime(const float* __restrict__ W2, const float* __restrict__ M1,
                         const float* __restrict__ b2, const float* __restrict__ c1,
                         float* __restrict__ Wp, float* __restrict__ cp) {
    int b = blockIdx.x, t = threadIdx.x;
    if (b < 64) {
        int idx = b * 256 + t;
        int i = idx >> 7, j = idx & 127;
        float acc = 0.f;
        for (int k = 0; k < 128; ++k) acc = fmaf(W2[i * 128 + k], M1[k * 128 + j], acc);
        Wp[idx] = acc;
    } else if (t < 128) {
        float acc = c1[t];
        for (int k = 0; k < 128; ++k) acc = fmaf(b2[k], M1[k * 128 + t], acc);
        cp[t] = acc;
    }
}

// ---------------- aggregation (dual-edge): t_i = dinv_i * (sum g_j + g_i) ----------------
// lanes 0-31 process even edge of a pair, lanes 32-63 the odd edge; each lane
// covers 4 features (uint2 = 4 fp16). Cross-half combine via shfl_xor(32).

__device__ inline void acc4(float4& a, uint2 g) {
    float2 lo = __half22float2(*reinterpret_cast<const __half2*>(&g.x));
    float2 hi = __half22float2(*reinterpret_cast<const __half2*>(&g.y));
    a.x += lo.x;
    a.y += lo.y;
    a.z += hi.x;
    a.w += hi.y;
}

template <typename IdxT>
__global__ __launch_bounds__(256) void k_agg_h2(const uint2* __restrict__ Ah2,  // [n*32]
                                                const int* __restrict__ rowptr,
                                                const IdxT* __restrict__ csr,
                                                const float* __restrict__ dinv,
                                                float4* __restrict__ out4, int n) {
    int wv = threadIdx.x >> 6;
    int lane = threadIdx.x & 63;
    int i = blockIdx.x * 4 + wv;
    if (i >= n) return;
    int half = lane >> 5;  // 0 or 1
    int fl = lane & 31;    // uint2 index within row (features 4*fl..4*fl+3)
    float di = dinv[i];
    float4 acc = make_float4(0.f, 0.f, 0.f, 0.f);
    int beg = rowptr[i], end = rowptr[i + 1];
    int e = beg;
    for (; e + 8 <= end; e += 8) {
        int s0 = (int)csr[e + half];
        int s1 = (int)csr[e + 2 + half];
        int s2 = (int)csr[e + 4 + half];
        int s3 = (int)csr[e + 6 + half];
        uint2 g0 = Ah2[s0 * 32 + fl];
        uint2 g1 = Ah2[s1 * 32 + fl];
        uint2 g2 = Ah2[s2 * 32 + fl];
        uint2 g3 = Ah2[s3 * 32 + fl];
        acc4(acc, g0);
        acc4(acc, g1);
        acc4(acc, g2);
        acc4(acc, g3);
    }
    for (; e + 2 <= end; e += 2) {
        int s0 = (int)csr[e + half];
        uint2 g0 = Ah2[s0 * 32 + fl];
        acc4(acc, g0);
    }
    if (e < end && half == 0) {
        int s0 = (int)csr[e];
        uint2 g0 = Ah2[s0 * 32 + fl];
        acc4(acc, g0);
    }
    // combine the two halves
    acc.x += __shfl_xor(acc.x, 32);
    acc.y += __shfl_xor(acc.y, 32);
    acc.z += __shfl_xor(acc.z, 32);
    acc.w += __shfl_xor(acc.w, 32);
    // self term + scale
    uint2 gs = Ah2[i * 32 + fl];
    acc4(acc, gs);
    acc.x *= di;
    acc.y *= di;
    acc.z *= di;
    acc.w *= di;
    if (half == 0) out4[i * 32 + fl] = acc;
}

// ---------------- GEMM: out = epilogue(A @ W + bias) ----------------
// MODE 0: out[N,128] = fp16( dinv[r] * relu(A@W + bias) )   (pre-scaled for next agg)
// MODE 1: out[N,1]   = relu(A@W + bias) . m2 + m2b[0]       (fp32)

template <int MODE>
__global__ __launch_bounds__(256) void k_gemm(const float* __restrict__ A,
                                              const float* __restrict__ W,
                                              const float* __restrict__ bias,
                                              const float* __restrict__ dinv,
                                              const float* __restrict__ m2,
                                              const float* __restrict__ m2b,
                                              void* __restrict__ outv, int n) {
    __shared__ float Ht[16 * 64];    // k-major: Ht[k][row]
    __shared__ float Wt[16 * 128];   // Wt[k][col]
    int tid = threadIdx.x;
    int rg = tid >> 4;   // rows rg*4 .. rg*4+3
    int cg = tid & 15;   // cols cg*8 .. cg*8+7
    int r0 = blockIdx.x * 64;

    float acc[4][8];
#pragma unroll
    for (int ri = 0; ri < 4; ++ri)
#pragma unroll
        for (int ci = 0; ci < 8; ++ci) acc[ri][ci] = 0.f;

    for (int k0 = 0; k0 < 128; k0 += 16) {
        {
            int row = tid >> 2;
            int kq = tid & 3;
            int grow = r0 + row;
            if (grow > n - 1) grow = n - 1;
            float4 v = *reinterpret_cast<const float4*>(&A[grow * 128 + k0 + kq * 4]);
            Ht[(kq * 4 + 0) * 64 + row] = v.x;
            Ht[(kq * 4 + 1) * 64 + row] = v.y;
            Ht[(kq * 4 + 2) * 64 + row] = v.z;
            Ht[(kq * 4 + 3) * 64 + row] = v.w;
        }
        for (int q = tid; q < 512; q += 256) {
            int kk = q >> 5;
            int cc = (q & 31) * 4;
            *reinterpret_cast<float4*>(&Wt[kk * 128 + cc]) =
                *reinterpret_cast<const float4*>(&W[(k0 + kk) * 128 + cc]);
        }
        __syncthreads();
#pragma unroll
        for (int k = 0; k < 16; ++k) {
            float4 a = *reinterpret_cast<float4*>(&Ht[k * 64 + rg * 4]);
            float4 b0 = *reinterpret_cast<float4*>(&Wt[k * 128 + cg * 8]);
            float4 b1 = *reinterpret_cast<float4*>(&Wt[k * 128 + cg * 8 + 4]);
            float av[4] = {a.x, a.y, a.z, a.w};
            float bv[8] = {b0.x, b0.y, b0.z, b0.w, b1.x, b1.y, b1.z, b1.w};
#pragma unroll
            for (int ri = 0; ri < 4; ++ri)
#pragma unroll
                for (int ci = 0; ci < 8; ++ci)
                    acc[ri][ci] = fmaf(av[ri], bv[ci], acc[ri][ci]);
        }
        __syncthreads();
    }

    float4 bb0 = *reinterpret_cast<const float4*>(&bias[cg * 8]);
    float4 bb1 = *reinterpret_cast<const float4*>(&bias[cg * 8 + 4]);
    float bv[8] = {bb0.x, bb0.y, bb0.z, bb0.w, bb1.x, bb1.y, bb1.z, bb1.w};

    if (MODE == 0) {
        __half* outh = (__half*)outv;
#pragma unroll
        for (int ri = 0; ri < 4; ++ri) {
            int r = r0 + rg * 4 + ri;
            if (r < n) {
                float dr = dinv[r];
                __half ho[8];
#pragma unroll
                for (int ci = 0; ci < 8; ++ci)
                    ho[ci] = __float2half(dr * fmaxf(acc[ri][ci] + bv[ci], 0.f));
                *reinterpret_cast<uint4*>(&outh[r * 128 + cg * 8]) =
                    *reinterpret_cast<const uint4*>(ho);
            }
        }
    } else {
        float* out = (float*)outv;
        float4 mm0 = *reinterpret_cast<const float4*>(&m2[cg * 8]);
        float4 mm1 = *reinterpret_cast<const float4*>(&m2[cg * 8 + 4]);
        float mv[8] = {mm0.x, mm0.y, mm0.z, mm0.w, mm1.x, mm1.y, mm1.z, mm1.w};
        float m2bv = m2b[0];
#pragma unroll
        for (int ri = 0; ri < 4; ++ri) {
            float p = 0.f;
#pragma unroll
            for (int ci = 0; ci < 8; ++ci) {
                float v = fmaxf(acc[ri][ci] + bv[ci], 0.f);
                p = fmaf(v, mv[ci], p);
            }
            p += __shfl_xor(p, 1);
            p += __shfl_xor(p, 2);
            p += __shfl_xor(p, 4);
            p += __shfl_xor(p, 8);
            int r = r0 + rg * 4 + ri;
            if (cg == 0 && r < n) out[r] = p + m2bv;
        }
    }
}

// ---------------- launch ----------------

extern "C" void kernel_launch(void* const* d_in, const int* in_sizes, int n_in,
                              void* d_out, int out_size, void* d_ws, size_t ws_size,
                              hipStream_t stream) {
    const float* x = (const float*)d_in[0];
    const int* ei = (const int*)d_in[1];
    const float* W0 = (const float*)d_in[2];
    const float* b0 = (const float*)d_in[3];
    const float* W1 = (const float*)d_in[4];
    const float* b1 = (const float*)d_in[5];
    const float* W2 = (const float*)d_in[6];
    const float* b2 = (const float*)d_in[7];
    const float* M1 = (const float*)d_in[8];
    const float* c1 = (const float*)d_in[9];
    const float* m2 = (const float*)d_in[10];
    const float* m2b = (const float*)d_in[11];
    float* out = (float*)d_out;

    int N = in_sizes[0] / D;
    int E = in_sizes[1] / 2;
    const int* src = ei;
    const int* dst = ei + E;

    char* ws = (char*)d_ws;
    size_t off = 0;
    auto alloc = [&](size_t bytes) -> void* {
        void* p = ws + off;
        off += (bytes + 255) & ~(size_t)255;
        return p;
    };

    int gN = (N + 255) / 256;
    int gE = (E + 255) / 256;
    int gAgg = (N + 3) / 4;
    int gGemm = (N + 63) / 64;
    int nElem4 = N * D / 4;
    int gCvt = (nElem4 + 255) / 256;

    float* bufT = (float*)alloc((size_t)N * D * 4);      // agg out / gemm in (fp32)
    __half* bufH = (__half*)alloc((size_t)N * D * 2);    // gemm out / agg in (fp16, dinv-scaled)
    __half* xh = (__half*)alloc((size_t)N * D * 2);      // fp16 dinv-scaled x
    int* cnt = (int*)alloc((size_t)N * 4);
    float* dinv = (float*)alloc((size_t)N * 4);
    int* rowptr = (int*)alloc((size_t)(N + 1) * 4);
    int* cursor = (int*)alloc((size_t)N * 4);
    void* csr = alloc((size_t)E * 4);  // ushort (E*2) or uint (E*4)
    float* Wp = (float*)alloc((size_t)D * D * 4);
    float* cp = (float*)alloc((size_t)D * 4);
    int* bsum = (int*)alloc((size_t)gN * 4);

    bool small_idx = (N <= 65535);

    int zc = (N + 3) / 4;
    k_zero<<<(zc + 255) / 256, 256, 0, stream>>>((int4*)cnt, zc);
    k_count<<<gE, 256, 0, stream>>>(dst, cnt, E);
    k_deg_stats<<<gN, 256, 0, stream>>>(cnt, dinv, bsum, N);
    k_scan_bsums<<<1, 1024, 0, stream>>>(bsum, gN, rowptr, N);
    k_local_scan<<<gN, 256, 0, stream>>>(cnt, bsum, rowptr, cursor, N);
    if (small_idx)
        k_fill<ushort><<<gE, 256, 0, stream>>>(src, dst, cursor, (ushort*)csr, E);
    else
        k_fill<uint><<<gE, 256, 0, stream>>>(src, dst, cursor, (uint*)csr, E);
    k_cvt_h<<<gCvt, 256, 0, stream>>>(x, dinv, xh, nElem4);
    k_wprime<<<65, 256, 0, stream>>>(W2, M1, b2, c1, Wp, cp);

    auto agg = [&](const __half* in_h, float* out_t) {
        if (small_idx)
            k_agg_h2<ushort><<<gAgg, 256, 0, stream>>>((const uint2*)in_h, rowptr,
                                                       (const ushort*)csr, dinv,
                                                       (float4*)out_t, N);
        else
            k_agg_h2<uint><<<gAgg, 256, 0, stream>>>((const uint2*)in_h, rowptr,
                                                     (const uint*)csr, dinv,
                                                     (float4*)out_t, N);
    };

    // layer 0
    agg(xh, bufT);
    k_gemm<0><<<gGemm, 256, 0, stream>>>(bufT, W0, b0, dinv, nullptr, nullptr, bufH, N);
    // layer 1
    agg(bufH, bufT);
    k_gemm<0><<<gGemm, 256, 0, stream>>>(bufT, W1, b1, dinv, nullptr, nullptr, bufH, N);
    // layer 2 + fused MLP head
    agg(bufH, bufT);
    k_gemm<1><<<gGemm, 256, 0, stream>>>(bufT, Wp, cp, dinv, m2, m2b, out, N);
}

// Round 7
// 211.832 us; speedup vs baseline: 1.6640x; 1.2813x over previous
//
#include <hip/hip_runtime.h>
#include <hip/hip_fp16.h>

constexpr int D = 128;

typedef _Float16 half8 __attribute__((ext_vector_type(8)));
typedef float f32x4 __attribute__((ext_vector_type(4)));

// ---------------- small utility ----------------

__global__ void k_zero(int4* __restrict__ p, int n4) {
    int i = blockIdx.x * 256 + threadIdx.x;
    if (i < n4) p[i] = make_int4(0, 0, 0, 0);
}

// ---------------- CSR build ----------------

__global__ void k_count(const int* __restrict__ dst, int* __restrict__ cnt, int E) {
    int e = blockIdx.x * 256 + threadIdx.x;
    if (e < E) atomicAdd(&cnt[dst[e]], 1);
}

__global__ __launch_bounds__(256) void k_deg_stats(const int* __restrict__ cnt,
                                                   float* __restrict__ dinv,
                                                   int* __restrict__ bsum, int n) {
    __shared__ int sm[256];
    int tid = threadIdx.x;
    int i = blockIdx.x * 256 + tid;
    int c = (i < n) ? cnt[i] : 0;
    if (i < n) dinv[i] = rsqrtf((float)(c + 1));  // +1 self-loop
    sm[tid] = c;
    __syncthreads();
    for (int off = 128; off > 0; off >>= 1) {
        if (tid < off) sm[tid] += sm[tid + off];
        __syncthreads();
    }
    if (tid == 0) bsum[blockIdx.x] = sm[0];
}

__global__ __launch_bounds__(1024) void k_scan_bsums(int* __restrict__ bsum, int nb,
                                                     int* __restrict__ rowptr, int n) {
    __shared__ int sm[1024];
    int tid = threadIdx.x;
    int v = (tid < nb) ? bsum[tid] : 0;
    sm[tid] = v;
    __syncthreads();
    for (int off = 1; off < 1024; off <<= 1) {
        int t = (tid >= off) ? sm[tid - off] : 0;
        __syncthreads();
        sm[tid] += t;
        __syncthreads();
    }
    if (tid < nb) bsum[tid] = sm[tid] - v;  // exclusive
    if (tid == 1023) rowptr[n] = sm[1023];
}

__global__ __launch_bounds__(256) void k_local_scan(const int* __restrict__ cnt,
                                                    const int* __restrict__ bsum,
                                                    int* __restrict__ rowptr,
                                                    int* __restrict__ cursor, int n) {
    __shared__ int sm[256];
    int tid = threadIdx.x;
    int i = blockIdx.x * 256 + tid;
    int v = (i < n) ? cnt[i] : 0;
    sm[tid] = v;
    __syncthreads();
    for (int off = 1; off < 256; off <<= 1) {
        int t = (tid >= off) ? sm[tid - off] : 0;
        __syncthreads();
        sm[tid] += t;
        __syncthreads();
    }
    if (i < n) {
        int rp = bsum[blockIdx.x] + sm[tid] - v;
        rowptr[i] = rp;
        cursor[i] = rp;
    }
}

template <typename IdxT>
__global__ void k_fill(const int* __restrict__ src, const int* __restrict__ dst,
                       int* __restrict__ cursor, IdxT* __restrict__ csr, int E) {
    int e = blockIdx.x * 256 + threadIdx.x;
    if (e < E) {
        int s = src[e], d = dst[e];
        int p = atomicAdd(&cursor[d], 1);
        csr[p] = (IdxT)s;
    }
}

// ---------------- fp32 -> fp16 with dinv pre-scale ----------------

__global__ void k_cvt_h(const float* __restrict__ in, const float* __restrict__ dinv,
                        __half* __restrict__ outh, int n4) {
    int i = blockIdx.x * 256 + threadIdx.x;
    if (i < n4) {
        float4 v = reinterpret_cast<const float4*>(in)[i];
        float dd = dinv[i >> 5];  // 32 float4 per row of 128
        __half ho[4] = {__float2half(v.x * dd), __float2half(v.y * dd),
                        __float2half(v.z * dd), __float2half(v.w * dd)};
        reinterpret_cast<uint2*>(outh)[i] = *reinterpret_cast<uint2*>(ho);
    }
}

// ---------------- W' = W2 @ M1 ; c' = b2 @ M1 + c1 ----------------

__global__ void k_wprime(const float* __restrict__ W2, const float* __restrict__ M1,
                         const float* __restrict__ b2, const float* __restrict__ c1,
                         float* __restrict__ Wp, float* __restrict__ cp) {
    int b = blockIdx.x, t = threadIdx.x;
    if (b < 64) {
        int idx = b * 256 + t;
        int i = idx >> 7, j = idx & 127;
        float acc = 0.f;
        for (int k = 0; k < 128; ++k) acc = fmaf(W2[i * 128 + k], M1[k * 128 + j], acc);
        Wp[idx] = acc;
    } else if (t < 128) {
        float acc = c1[t];
        for (int k = 0; k < 128; ++k) acc = fmaf(b2[k], M1[k * 128 + t], acc);
        cp[t] = acc;
    }
}

// ---------------- W -> fp16 fragment layout for mfma_f32_16x16x32_f16 ----------------
// Wf[((kk*8 + c)*64 + l)*8 + j] = W[kk*32 + (l>>4)*8 + j][c*16 + (l&15)]
// so B-fragment (kk, c) is one contiguous 1KB block; lane l reads 16B at offset l*16.

__global__ void k_cvt_w(const float* __restrict__ W0, const float* __restrict__ W1,
                        const float* __restrict__ Wp, __half* __restrict__ Wf0,
                        __half* __restrict__ Wf1, __half* __restrict__ Wfp) {
    int m = blockIdx.x >> 6;  // matrix select
    int idx = (blockIdx.x & 63) * 256 + threadIdx.x;
    int j = idx & 7;
    int l = (idx >> 3) & 63;
    int c = (idx >> 9) & 7;
    int kk = (idx >> 12) & 3;
    int row = kk * 32 + (l >> 4) * 8 + j;
    int col = c * 16 + (l & 15);
    const float* W = (m == 0) ? W0 : (m == 1) ? W1 : Wp;
    __half* Wf = (m == 0) ? Wf0 : (m == 1) ? Wf1 : Wfp;
    Wf[idx] = __float2half(W[row * 128 + col]);
}

// ---------------- aggregation (dual-edge): t_i = fp16( dinv_i * (sum g_j + g_i) ) ----------------

__device__ inline void acc4(float4& a, uint2 g) {
    float2 lo = __half22float2(*reinterpret_cast<const __half2*>(&g.x));
    float2 hi = __half22float2(*reinterpret_cast<const __half2*>(&g.y));
    a.x += lo.x;
    a.y += lo.y;
    a.z += hi.x;
    a.w += hi.y;
}

template <typename IdxT>
__global__ __launch_bounds__(256) void k_agg_h2(const uint2* __restrict__ Ah2,  // [n*32]
                                                const int* __restrict__ rowptr,
                                                const IdxT* __restrict__ csr,
                                                const float* __restrict__ dinv,
                                                __half* __restrict__ outh, int n) {
    int wv = threadIdx.x >> 6;
    int lane = threadIdx.x & 63;
    int i = blockIdx.x * 4 + wv;
    if (i >= n) return;
    int half = lane >> 5;  // 0 or 1
    int fl = lane & 31;    // uint2 index within row (features 4*fl..4*fl+3)
    float di = dinv[i];
    float4 acc = make_float4(0.f, 0.f, 0.f, 0.f);
    int beg = rowptr[i], end = rowptr[i + 1];
    int e = beg;
    for (; e + 8 <= end; e += 8) {
        int s0 = (int)csr[e + half];
        int s1 = (int)csr[e + 2 + half];
        int s2 = (int)csr[e + 4 + half];
        int s3 = (int)csr[e + 6 + half];
        uint2 g0 = Ah2[s0 * 32 + fl];
        uint2 g1 = Ah2[s1 * 32 + fl];
        uint2 g2 = Ah2[s2 * 32 + fl];
        uint2 g3 = Ah2[s3 * 32 + fl];
        acc4(acc, g0);
        acc4(acc, g1);
        acc4(acc, g2);
        acc4(acc, g3);
    }
    for (; e + 2 <= end; e += 2) {
        int s0 = (int)csr[e + half];
        uint2 g0 = Ah2[s0 * 32 + fl];
        acc4(acc, g0);
    }
    if (e < end && half == 0) {
        int s0 = (int)csr[e];
        uint2 g0 = Ah2[s0 * 32 + fl];
        acc4(acc, g0);
    }
    // combine the two halves
    acc.x += __shfl_xor(acc.x, 32);
    acc.y += __shfl_xor(acc.y, 32);
    acc.z += __shfl_xor(acc.z, 32);
    acc.w += __shfl_xor(acc.w, 32);
    // self term + scale, emit fp16
    uint2 gs = Ah2[i * 32 + fl];
    acc4(acc, gs);
    if (half == 0) {
        __half ho[4] = {__float2half(di * acc.x), __float2half(di * acc.y),
                        __float2half(di * acc.z), __float2half(di * acc.w)};
        *reinterpret_cast<uint2*>(&outh[i * 128 + fl * 4]) =
            *reinterpret_cast<const uint2*>(ho);
    }
}

// ---------------- MFMA GEMM: out = epilogue(A_fp16 @ W_fp16 + bias) ----------------
// Block: 256 thr = 4 waves; block tile 64 rows; wave w: rows r0+w*16..+15, all 128 cols.
// Per wave: 8 col-frags x 4 K-steps of v_mfma_f32_16x16x32_f16. No LDS, no barriers.
// MODE 0: out[N,128] = fp16( dinv[r] * relu(h) )
// MODE 1: out[N,1]   = relu(h) . m2 + m2b[0]   (fp32)

template <int MODE>
__global__ __launch_bounds__(256) void k_gemm_mfma(const __half* __restrict__ A,
                                                   const __half* __restrict__ Wf,
                                                   const float* __restrict__ bias,
                                                   const float* __restrict__ dinv,
                                                   const float* __restrict__ m2,
                                                   const float* __restrict__ m2b,
                                                   void* __restrict__ outv, int n) {
    int tid = threadIdx.x;
    int w = tid >> 6;
    int l = tid & 63;
    int r0 = blockIdx.x * 64 + w * 16;
    int arow = r0 + (l & 15);
    if (arow > n - 1) arow = n - 1;
    int kb = (l >> 4) * 8;

    f32x4 acc[8];
#pragma unroll
    for (int c = 0; c < 8; ++c) acc[c] = (f32x4){0.f, 0.f, 0.f, 0.f};

#pragma unroll
    for (int kk = 0; kk < 4; ++kk) {
        half8 a = *reinterpret_cast<const half8*>(&A[arow * 128 + kk * 32 + kb]);
#pragma unroll
        for (int c = 0; c < 8; ++c) {
            half8 b = *reinterpret_cast<const half8*>(&Wf[((kk * 8 + c) * 64 + l) * 8]);
            acc[c] = __builtin_amdgcn_mfma_f32_16x16x32_f16(a, b, acc[c], 0, 0, 0);
        }
    }

    // D layout: col = c*16 + (l&15), row = r0 + (l>>4)*4 + reg
    float bv[8];
#pragma unroll
    for (int c = 0; c < 8; ++c) bv[c] = bias[c * 16 + (l & 15)];

    if (MODE == 0) {
        __half* outh = (__half*)outv;
#pragma unroll
        for (int reg = 0; reg < 4; ++reg) {
            int r = r0 + (l >> 4) * 4 + reg;
            if (r < n) {
                float dr = dinv[r];
#pragma unroll
                for (int c = 0; c < 8; ++c) {
                    float v = dr * fmaxf(acc[c][reg] + bv[c], 0.f);
                    outh[r * 128 + c * 16 + (l & 15)] = __float2half(v);
                }
            }
        }
    } else {
        float* out = (float*)outv;
        float mv[8];
#pragma unroll
        for (int c = 0; c < 8; ++c) mv[c] = m2[c * 16 + (l & 15)];
        float m2bv = m2b[0];
#pragma unroll
        for (int reg = 0; reg < 4; ++reg) {
            float p = 0.f;
#pragma unroll
            for (int c = 0; c < 8; ++c)
                p = fmaf(fmaxf(acc[c][reg] + bv[c], 0.f), mv[c], p);
            p += __shfl_xor(p, 1);
            p += __shfl_xor(p, 2);
            p += __shfl_xor(p, 4);
            p += __shfl_xor(p, 8);
            int r = r0 + (l >> 4) * 4 + reg;
            if ((l & 15) == 0 && r < n) out[r] = p + m2bv;
        }
    }
}

// ---------------- launch ----------------

extern "C" void kernel_launch(void* const* d_in, const int* in_sizes, int n_in,
                              void* d_out, int out_size, void* d_ws, size_t ws_size,
                              hipStream_t stream) {
    const float* x = (const float*)d_in[0];
    const int* ei = (const int*)d_in[1];
    const float* W0 = (const float*)d_in[2];
    const float* b0 = (const float*)d_in[3];
    const float* W1 = (const float*)d_in[4];
    const float* b1 = (const float*)d_in[5];
    const float* W2 = (const float*)d_in[6];
    const float* b2 = (const float*)d_in[7];
    const float* M1 = (const float*)d_in[8];
    const float* c1 = (const float*)d_in[9];
    const float* m2 = (const float*)d_in[10];
    const float* m2b = (const float*)d_in[11];
    float* out = (float*)d_out;

    int N = in_sizes[0] / D;
    int E = in_sizes[1] / 2;
    const int* src = ei;
    const int* dst = ei + E;

    char* ws = (char*)d_ws;
    size_t off = 0;
    auto alloc = [&](size_t bytes) -> void* {
        void* p = ws + off;
        off += (bytes + 255) & ~(size_t)255;
        return p;
    };

    int gN = (N + 255) / 256;
    int gE = (E + 255) / 256;
    int gAgg = (N + 3) / 4;
    int gGemm = (N + 63) / 64;
    int nElem4 = N * D / 4;
    int gCvt = (nElem4 + 255) / 256;

    __half* xh = (__half*)alloc((size_t)N * D * 2);     // fp16 dinv-scaled x
    __half* tbuf = (__half*)alloc((size_t)N * D * 2);   // agg out / gemm A in
    __half* gbuf = (__half*)alloc((size_t)N * D * 2);   // gemm out / agg in
    int* cnt = (int*)alloc((size_t)N * 4);
    float* dinv = (float*)alloc((size_t)N * 4);
    int* rowptr = (int*)alloc((size_t)(N + 1) * 4);
    int* cursor = (int*)alloc((size_t)N * 4);
    void* csr = alloc((size_t)E * 4);  // ushort (E*2) or uint (E*4)
    float* Wp = (float*)alloc((size_t)D * D * 4);
    float* cp = (float*)alloc((size_t)D * 4);
    __half* Wf0 = (__half*)alloc((size_t)D * D * 2);
    __half* Wf1 = (__half*)alloc((size_t)D * D * 2);
    __half* Wfp = (__half*)alloc((size_t)D * D * 2);
    int* bsum = (int*)alloc((size_t)gN * 4);

    bool small_idx = (N <= 65535);

    int zc = (N + 3) / 4;
    k_zero<<<(zc + 255) / 256, 256, 0, stream>>>((int4*)cnt, zc);
    k_count<<<gE, 256, 0, stream>>>(dst, cnt, E);
    k_deg_stats<<<gN, 256, 0, stream>>>(cnt, dinv, bsum, N);
    k_scan_bsums<<<1, 1024, 0, stream>>>(bsum, gN, rowptr, N);
    k_local_scan<<<gN, 256, 0, stream>>>(cnt, bsum, rowptr, cursor, N);
    if (small_idx)
        k_fill<ushort><<<gE, 256, 0, stream>>>(src, dst, cursor, (ushort*)csr, E);
    else
        k_fill<uint><<<gE, 256, 0, stream>>>(src, dst, cursor, (uint*)csr, E);
    k_cvt_h<<<gCvt, 256, 0, stream>>>(x, dinv, xh, nElem4);
    k_wprime<<<65, 256, 0, stream>>>(W2, M1, b2, c1, Wp, cp);
    k_cvt_w<<<192, 256, 0, stream>>>(W0, W1, Wp, Wf0, Wf1, Wfp);

    auto agg = [&](const __half* in_h, __half* out_t) {
        if (small_idx)
            k_agg_h2<ushort><<<gAgg, 256, 0, stream>>>((const uint2*)in_h, rowptr,
                                                       (const ushort*)csr, dinv, out_t, N);
        else
            k_agg_h2<uint><<<gAgg, 256, 0, stream>>>((const uint2*)in_h, rowptr,
                                                     (const uint*)csr, dinv, out_t, N);
    };

    // layer 0
    agg(xh, tbuf);
    k_gemm_mfma<0><<<gGemm, 256, 0, stream>>>(tbuf, Wf0, b0, dinv, nullptr, nullptr,
                                              gbuf, N);
    // layer 1
    agg(gbuf, tbuf);
    k_gemm_mfma<0><<<gGemm, 256, 0, stream>>>(tbuf, Wf1, b1, dinv, nullptr, nullptr,
                                              gbuf, N);
    // layer 2 + fused MLP head
    agg(gbuf, tbuf);
    k_gemm_mfma<1><<<gGemm, 256, 0, stream>>>(tbuf, Wfp, cp, dinv, m2, m2b, out, N);
}

// Round 8
// 196.733 us; speedup vs baseline: 1.7917x; 1.0767x over previous
//
#include <hip/hip_runtime.h>
#include <hip/hip_fp16.h>

constexpr int D = 128;

typedef _Float16 half8 __attribute__((ext_vector_type(8)));
typedef float f32x4 __attribute__((ext_vector_type(4)));

// ---------------- small utility ----------------

__global__ void k_zero(int4* __restrict__ p, int n4) {
    int i = blockIdx.x * 256 + threadIdx.x;
    if (i < n4) p[i] = make_int4(0, 0, 0, 0);
}

// ---------------- CSR build ----------------

__global__ void k_count(const int* __restrict__ dst, int* __restrict__ cnt, int E) {
    int e = blockIdx.x * 256 + threadIdx.x;
    if (e < E) atomicAdd(&cnt[dst[e]], 1);
}

__global__ __launch_bounds__(256) void k_deg_stats(const int* __restrict__ cnt,
                                                   float* __restrict__ dinv,
                                                   int* __restrict__ bsum, int n) {
    __shared__ int sm[256];
    int tid = threadIdx.x;
    int i = blockIdx.x * 256 + tid;
    int c = (i < n) ? cnt[i] : 0;
    if (i < n) dinv[i] = rsqrtf((float)(c + 1));  // +1 self-loop
    sm[tid] = c;
    __syncthreads();
    for (int off = 128; off > 0; off >>= 1) {
        if (tid < off) sm[tid] += sm[tid + off];
        __syncthreads();
    }
    if (tid == 0) bsum[blockIdx.x] = sm[0];
}

__global__ __launch_bounds__(1024) void k_scan_bsums(int* __restrict__ bsum, int nb,
                                                     int* __restrict__ rowptr, int n) {
    __shared__ int sm[1024];
    int tid = threadIdx.x;
    int v = (tid < nb) ? bsum[tid] : 0;
    sm[tid] = v;
    __syncthreads();
    for (int off = 1; off < 1024; off <<= 1) {
        int t = (tid >= off) ? sm[tid - off] : 0;
        __syncthreads();
        sm[tid] += t;
        __syncthreads();
    }
    if (tid < nb) bsum[tid] = sm[tid] - v;  // exclusive
    if (tid == 1023) rowptr[n] = sm[1023];
}

__global__ __launch_bounds__(256) void k_local_scan(const int* __restrict__ cnt,
                                                    const int* __restrict__ bsum,
                                                    int* __restrict__ rowptr,
                                                    int* __restrict__ cursor, int n) {
    __shared__ int sm[256];
    int tid = threadIdx.x;
    int i = blockIdx.x * 256 + tid;
    int v = (i < n) ? cnt[i] : 0;
    sm[tid] = v;
    __syncthreads();
    for (int off = 1; off < 256; off <<= 1) {
        int t = (tid >= off) ? sm[tid - off] : 0;
        __syncthreads();
        sm[tid] += t;
        __syncthreads();
    }
    if (i < n) {
        int rp = bsum[blockIdx.x] + sm[tid] - v;
        rowptr[i] = rp;
        cursor[i] = rp;
    }
}

template <typename IdxT>
__global__ void k_fill(const int* __restrict__ src, const int* __restrict__ dst,
                       int* __restrict__ cursor, IdxT* __restrict__ csr, int E) {
    int e = blockIdx.x * 256 + threadIdx.x;
    if (e < E) {
        int s = src[e], d = dst[e];
        int p = atomicAdd(&cursor[d], 1);
        csr[p] = (IdxT)s;
    }
}

// ---------------- fp32 -> fp16 with dinv pre-scale ----------------

__global__ void k_cvt_h(const float* __restrict__ in, const float* __restrict__ dinv,
                        __half* __restrict__ outh, int n4) {
    int i = blockIdx.x * 256 + threadIdx.x;
    if (i < n4) {
        float4 v = reinterpret_cast<const float4*>(in)[i];
        float dd = dinv[i >> 5];  // 32 float4 per row of 128
        __half ho[4] = {__float2half(v.x * dd), __float2half(v.y * dd),
                        __float2half(v.z * dd), __float2half(v.w * dd)};
        reinterpret_cast<uint2*>(outh)[i] = *reinterpret_cast<uint2*>(ho);
    }
}

// ---------------- W' = W2 @ M1 ; c' = b2 @ M1 + c1 ----------------

__global__ void k_wprime(const float* __restrict__ W2, const float* __restrict__ M1,
                         const float* __restrict__ b2, const float* __restrict__ c1,
                         float* __restrict__ Wp, float* __restrict__ cp) {
    int b = blockIdx.x, t = threadIdx.x;
    if (b < 64) {
        int idx = b * 256 + t;
        int i = idx >> 7, j = idx & 127;
        float acc = 0.f;
        for (int k = 0; k < 128; ++k) acc = fmaf(W2[i * 128 + k], M1[k * 128 + j], acc);
        Wp[idx] = acc;
    } else if (t < 128) {
        float acc = c1[t];
        for (int k = 0; k < 128; ++k) acc = fmaf(b2[k], M1[k * 128 + t], acc);
        cp[t] = acc;
    }
}

// ---------------- W -> fp16 fragment layout for mfma_f32_16x16x32_f16 ----------------
// Wf[((kk*8 + c)*64 + l)*8 + j] = W[kk*32 + (l>>4)*8 + j][c*16 + (l&15)]

__global__ void k_cvt_w(const float* __restrict__ W0, const float* __restrict__ W1,
                        const float* __restrict__ Wp, __half* __restrict__ Wf0,
                        __half* __restrict__ Wf1, __half* __restrict__ Wfp) {
    int m = blockIdx.x >> 6;  // matrix select
    int idx = (blockIdx.x & 63) * 256 + threadIdx.x;
    int j = idx & 7;
    int l = (idx >> 3) & 63;
    int c = (idx >> 9) & 7;
    int kk = (idx >> 12) & 3;
    int row = kk * 32 + (l >> 4) * 8 + j;
    int col = c * 16 + (l & 15);
    const float* W = (m == 0) ? W0 : (m == 1) ? W1 : Wp;
    __half* Wf = (m == 0) ? Wf0 : (m == 1) ? Wf1 : Wfp;
    Wf[idx] = __float2half(W[row * 128 + col]);
}

// ---------------- aggregation (quad-edge, register-resident indices) ----------------
// t_i = fp16( dinv_i * (sum_{j->i} g_j + g_i) ), g fp16 dinv-prescaled.
// Wave per row. Indices for up to 64 edges loaded in one coalesced 2B/lane load,
// broadcast via shfl. 16 lanes per edge (uint4 = 8 fp16), 4 edges per load-group,
// 16 edges (4 independent gathers) in flight per iteration. Masked fmaf for tails.

__device__ inline void accm(float* a, uint4 g, float m) {
    float2 p0 = __half22float2(*reinterpret_cast<const __half2*>(&g.x));
    float2 p1 = __half22float2(*reinterpret_cast<const __half2*>(&g.y));
    float2 p2 = __half22float2(*reinterpret_cast<const __half2*>(&g.z));
    float2 p3 = __half22float2(*reinterpret_cast<const __half2*>(&g.w));
    a[0] = fmaf(m, p0.x, a[0]);
    a[1] = fmaf(m, p0.y, a[1]);
    a[2] = fmaf(m, p1.x, a[2]);
    a[3] = fmaf(m, p1.y, a[3]);
    a[4] = fmaf(m, p2.x, a[4]);
    a[5] = fmaf(m, p2.y, a[5]);
    a[6] = fmaf(m, p3.x, a[6]);
    a[7] = fmaf(m, p3.y, a[7]);
}

template <typename IdxT>
__global__ __launch_bounds__(256) void k_agg_h4(const uint4* __restrict__ Ah4,  // [n*16]
                                                const int* __restrict__ rowptr,
                                                const IdxT* __restrict__ csr,
                                                const float* __restrict__ dinv,
                                                uint4* __restrict__ outh4, int n) {
    int wv = threadIdx.x >> 6;
    int lane = threadIdx.x & 63;
    int i = blockIdx.x * 4 + wv;
    if (i >= n) return;
    int qg = lane >> 4;  // 0..3: edge subgroup
    int fl = lane & 15;  // uint4 index within row (features fl*8..fl*8+7)
    float a[8];
#pragma unroll
    for (int j = 0; j < 8; ++j) a[j] = 0.f;
    int beg = rowptr[i], end = rowptr[i + 1];
    for (int base = beg; base < end; base += 64) {
        int cnt = end - base;
        if (cnt > 64) cnt = 64;
        int idxv = (base + lane < end) ? (int)csr[base + lane] : 0;
        for (int e = 0; e < cnt; e += 16) {
            int k0 = e + qg;
            int k1 = e + qg + 4;
            int k2 = e + qg + 8;
            int k3 = e + qg + 12;
            int s0 = __shfl(idxv, k0);
            int s1 = __shfl(idxv, k1);
            int s2 = __shfl(idxv, k2);
            int s3 = __shfl(idxv, k3);
            uint4 g0 = Ah4[s0 * 16 + fl];
            uint4 g1 = Ah4[s1 * 16 + fl];
            uint4 g2 = Ah4[s2 * 16 + fl];
            uint4 g3 = Ah4[s3 * 16 + fl];
            float m0 = (k0 < cnt) ? 1.f : 0.f;
            float m1 = (k1 < cnt) ? 1.f : 0.f;
            float m2 = (k2 < cnt) ? 1.f : 0.f;
            float m3 = (k3 < cnt) ? 1.f : 0.f;
            accm(a, g0, m0);
            accm(a, g1, m1);
            accm(a, g2, m2);
            accm(a, g3, m3);
        }
    }
    // combine the four edge subgroups (lanes differing in bits 4-5)
#pragma unroll
    for (int j = 0; j < 8; ++j) {
        a[j] += __shfl_xor(a[j], 16);
        a[j] += __shfl_xor(a[j], 32);
    }
    if (qg == 0) {
        uint4 gs = Ah4[i * 16 + fl];
        accm(a, gs, 1.f);  // self term
        float di = dinv[i];
        __half ho[8];
#pragma unroll
        for (int j = 0; j < 8; ++j) ho[j] = __float2half(di * a[j]);
        outh4[i * 16 + fl] = *reinterpret_cast<const uint4*>(ho);
    }
}

// ---------------- MFMA GEMM: out = epilogue(A_fp16 @ W_fp16 + bias) ----------------
// MODE 0: out[N,128] = fp16( dinv[r] * relu(h) )
// MODE 1: out[N,1]   = relu(h) . m2 + m2b[0]   (fp32)

template <int MODE>
__global__ __launch_bounds__(256) void k_gemm_mfma(const __half* __restrict__ A,
                                                   const __half* __restrict__ Wf,
                                                   const float* __restrict__ bias,
                                                   const float* __restrict__ dinv,
                                                   const float* __restrict__ m2,
                                                   const float* __restrict__ m2b,
                                                   void* __restrict__ outv, int n) {
    int tid = threadIdx.x;
    int w = tid >> 6;
    int l = tid & 63;
    int r0 = blockIdx.x * 64 + w * 16;
    int arow = r0 + (l & 15);
    if (arow > n - 1) arow = n - 1;
    int kb = (l >> 4) * 8;

    f32x4 acc[8];
#pragma unroll
    for (int c = 0; c < 8; ++c) acc[c] = (f32x4){0.f, 0.f, 0.f, 0.f};

#pragma unroll
    for (int kk = 0; kk < 4; ++kk) {
        half8 a = *reinterpret_cast<const half8*>(&A[arow * 128 + kk * 32 + kb]);
#pragma unroll
        for (int c = 0; c < 8; ++c) {
            half8 b = *reinterpret_cast<const half8*>(&Wf[((kk * 8 + c) * 64 + l) * 8]);
            acc[c] = __builtin_amdgcn_mfma_f32_16x16x32_f16(a, b, acc[c], 0, 0, 0);
        }
    }

    float bv[8];
#pragma unroll
    for (int c = 0; c < 8; ++c) bv[c] = bias[c * 16 + (l & 15)];

    if (MODE == 0) {
        __half* outh = (__half*)outv;
#pragma unroll
        for (int reg = 0; reg < 4; ++reg) {
            int r = r0 + (l >> 4) * 4 + reg;
            if (r < n) {
                float dr = dinv[r];
#pragma unroll
                for (int c = 0; c < 8; ++c) {
                    float v = dr * fmaxf(acc[c][reg] + bv[c], 0.f);
                    outh[r * 128 + c * 16 + (l & 15)] = __float2half(v);
                }
            }
        }
    } else {
        float* out = (float*)outv;
        float mv[8];
#pragma unroll
        for (int c = 0; c < 8; ++c) mv[c] = m2[c * 16 + (l & 15)];
        float m2bv = m2b[0];
#pragma unroll
        for (int reg = 0; reg < 4; ++reg) {
            float p = 0.f;
#pragma unroll
            for (int c = 0; c < 8; ++c)
                p = fmaf(fmaxf(acc[c][reg] + bv[c], 0.f), mv[c], p);
            p += __shfl_xor(p, 1);
            p += __shfl_xor(p, 2);
            p += __shfl_xor(p, 4);
            p += __shfl_xor(p, 8);
            int r = r0 + (l >> 4) * 4 + reg;
            if ((l & 15) == 0 && r < n) out[r] = p + m2bv;
        }
    }
}

// ---------------- launch ----------------

extern "C" void kernel_launch(void* const* d_in, const int* in_sizes, int n_in,
                              void* d_out, int out_size, void* d_ws, size_t ws_size,
                              hipStream_t stream) {
    const float* x = (const float*)d_in[0];
    const int* ei = (const int*)d_in[1];
    const float* W0 = (const float*)d_in[2];
    const float* b0 = (const float*)d_in[3];
    const float* W1 = (const float*)d_in[4];
    const float* b1 = (const float*)d_in[5];
    const float* W2 = (const float*)d_in[6];
    const float* b2 = (const float*)d_in[7];
    const float* M1 = (const float*)d_in[8];
    const float* c1 = (const float*)d_in[9];
    const float* m2 = (const float*)d_in[10];
    const float* m2b = (const float*)d_in[11];
    float* out = (float*)d_out;

    int N = in_sizes[0] / D;
    int E = in_sizes[1] / 2;
    const int* src = ei;
    const int* dst = ei + E;

    char* ws = (char*)d_ws;
    size_t off = 0;
    auto alloc = [&](size_t bytes) -> void* {
        void* p = ws + off;
        off += (bytes + 255) & ~(size_t)255;
        return p;
    };

    int gN = (N + 255) / 256;
    int gE = (E + 255) / 256;
    int gAgg = (N + 3) / 4;
    int gGemm = (N + 63) / 64;
    int nElem4 = N * D / 4;
    int gCvt = (nElem4 + 255) / 256;

    __half* xh = (__half*)alloc((size_t)N * D * 2);     // fp16 dinv-scaled x
    __half* tbuf = (__half*)alloc((size_t)N * D * 2);   // agg out / gemm A in
    __half* gbuf = (__half*)alloc((size_t)N * D * 2);   // gemm out / agg in
    int* cnt = (int*)alloc((size_t)N * 4);
    float* dinv = (float*)alloc((size_t)N * 4);
    int* rowptr = (int*)alloc((size_t)(N + 1) * 4);
    int* cursor = (int*)alloc((size_t)N * 4);
    void* csr = alloc((size_t)E * 4);  // ushort (E*2) or uint (E*4)
    float* Wp = (float*)alloc((size_t)D * D * 4);
    float* cp = (float*)alloc((size_t)D * 4);
    __half* Wf0 = (__half*)alloc((size_t)D * D * 2);
    __half* Wf1 = (__half*)alloc((size_t)D * D * 2);
    __half* Wfp = (__half*)alloc((size_t)D * D * 2);
    int* bsum = (int*)alloc((size_t)gN * 4);

    bool small_idx = (N <= 65535);

    int zc = (N + 3) / 4;
    k_zero<<<(zc + 255) / 256, 256, 0, stream>>>((int4*)cnt, zc);
    k_count<<<gE, 256, 0, stream>>>(dst, cnt, E);
    k_deg_stats<<<gN, 256, 0, stream>>>(cnt, dinv, bsum, N);
    k_scan_bsums<<<1, 1024, 0, stream>>>(bsum, gN, rowptr, N);
    k_local_scan<<<gN, 256, 0, stream>>>(cnt, bsum, rowptr, cursor, N);
    if (small_idx)
        k_fill<ushort><<<gE, 256, 0, stream>>>(src, dst, cursor, (ushort*)csr, E);
    else
        k_fill<uint><<<gE, 256, 0, stream>>>(src, dst, cursor, (uint*)csr, E);
    k_cvt_h<<<gCvt, 256, 0, stream>>>(x, dinv, xh, nElem4);
    k_wprime<<<65, 256, 0, stream>>>(W2, M1, b2, c1, Wp, cp);
    k_cvt_w<<<192, 256, 0, stream>>>(W0, W1, Wp, Wf0, Wf1, Wfp);

    auto agg = [&](const __half* in_h, __half* out_t) {
        if (small_idx)
            k_agg_h4<ushort><<<gAgg, 256, 0, stream>>>((const uint4*)in_h, rowptr,
                                                       (const ushort*)csr, dinv,
                                                       (uint4*)out_t, N);
        else
            k_agg_h4<uint><<<gAgg, 256, 0, stream>>>((const uint4*)in_h, rowptr,
                                                     (const uint*)csr, dinv,
                                                     (uint4*)out_t, N);
    };

    // layer 0
    agg(xh, tbuf);
    k_gemm_mfma<0><<<gGemm, 256, 0, stream>>>(tbuf, Wf0, b0, dinv, nullptr, nullptr,
                                              gbuf, N);
    // layer 1
    agg(gbuf, tbuf);
    k_gemm_mfma<0><<<gGemm, 256, 0, stream>>>(tbuf, Wf1, b1, dinv, nullptr, nullptr,
                                              gbuf, N);
    // layer 2 + fused MLP head
    agg(gbuf, tbuf);
    k_gemm_mfma<1><<<gGemm, 256, 0, stream>>>(tbuf, Wfp, cp, dinv, m2, m2b, out, N);
}